// Round 8
// baseline (92.004 us; speedup 1.0000x reference)
//
#include <hip/hip_runtime.h>
#include <float.h>

// loss = (1/(E(E-1))) * sum_{i,j: t_i != t_j} relu(pred[i,t_j] - (f_own[j]-1)) / (N[t_i] N[t_j])
// Identity: sum_k relu(p - thr_k) = NPAD*p - sum_k min(p, thr_k) with FLT_MAX padding.
// => no sort, no search, no inner-loop LDS. Thread = class; thresholds live in float4
// registers (static indices); rows stream coalesced; all VALU ops independent.
// Diagonal (c == t_i) removed analytically via k_diag. Padding width picked by uniform
// branch on the measured max class count (<=16 / <=24 / <=32; >32 -> global fallback).

#define CCLS 1000
#define PADF 64     // float slots per class in thrP (fallback supports count <= 64)
#define TPB 256
#define CCH 250     // classes per chunk -> 4 chunks
#define NCH 4
#define NRBLK 256   // row blocks per chunk: RPB = 12288/256 = 48
#define RMAX 64

__global__ void k_init(float4* thrP4, int* fill, float* scal, int* flags) {
    int t = blockIdx.x * 256 + threadIdx.x;
    if (t < CCLS * PADF / 4) thrP4[t] = make_float4(FLT_MAX, FLT_MAX, FLT_MAX, FLT_MAX);
    if (t < CCLS) fill[t] = 0;
    if (t < 8) { scal[t] = 0.f; flags[t] = 0; }
}

__global__ void k_scatter(const float* __restrict__ pred, const int* __restrict__ target,
                          int* fill, float* thrP, int B) {
    int j = blockIdx.x * 256 + threadIdx.x;
    if (j >= B) return;
    int tj = target[j];
    float fo = pred[(size_t)j * CCLS + tj];  // f_own[j]
    int pos = atomicAdd(&fill[tj], 1);
    if (pos < PADF) thrP[tj * PADF + pos] = fo - 1.0f;
}

// wave per class: E, invN, max count, and diagonal sum D = sum_c sum_{i:t_i=c} F_c(f_own_i)/N_c^2
// with F_c(x) = sum_k relu(x - thr_k) over class-c thresholds. Order-free, via shuffles.
__global__ __launch_bounds__(256) void k_diag(const int* __restrict__ fill,
                                              const float* __restrict__ thrP,
                                              float* invN, float* scal, int* flags) {
    int c = (blockIdx.x * 256 + threadIdx.x) >> 6;
    int lane = threadIdx.x & 63;
    if (c >= CCLS) return;
    int cnt = fill[c];
    int cl = min(cnt, PADF);
    float v = (lane < cl) ? thrP[c * PADF + lane] : FLT_MAX;
    float vp1 = v + 1.0f;            // f_own of this element
    float F = 0.f;
    for (int k = 0; k < cl; ++k) {
        float u = __shfl(v, k);
        F += fmaxf(vp1 - u, 0.f);
    }
    if (lane >= cl) F = 0.f;
    for (int o = 32; o; o >>= 1) F += __shfl_down(F, o);
    if (lane == 0) {
        if (cnt > 0) {
            float ic = 1.0f / (float)cnt;
            invN[c] = ic;
            atomicAdd(&scal[0], 1.0f);        // E
            atomicAdd(&scal[2], F * ic * ic); // diagonal
        } else {
            invN[c] = 0.f;
        }
        atomicMax(&flags[1], cnt);            // max class count
    }
}

// NQ = number of float4 threshold registers (4*NQ padded slots)
#define BODY(NQ)                                                                  \
    {                                                                             \
        float4 tq[NQ];                                                            \
        _Pragma("unroll") for (int q = 0; q < NQ; ++q) tq[q] = tp4[q];            \
        const float* pp = pred + (size_t)rbase * CCLS + c;                        \
        _Pragma("unroll 2") for (int r = 0; r < rows; ++r) {                      \
            const float p = pp[(size_t)r * CCLS];                                 \
            const float wt = rowW[r];                                             \
            float s0 = 0.f, s1 = 0.f, s2 = 0.f, s3 = 0.f;                         \
            _Pragma("unroll") for (int q = 0; q < NQ; ++q) {                      \
                s0 += fminf(p, tq[q].x);                                          \
                s1 += fminf(p, tq[q].y);                                          \
                s2 += fminf(p, tq[q].z);                                          \
                s3 += fminf(p, tq[q].w);                                          \
            }                                                                     \
            const float contrib = fmaf((float)(4 * NQ), p, -((s0 + s1) + (s2 + s3))); \
            acc = fmaf(contrib, wt, acc);                                         \
        }                                                                         \
    }

__global__ __launch_bounds__(TPB) void k_main(const float* __restrict__ pred,
        const int* __restrict__ target, const float* __restrict__ thrP,
        const float* __restrict__ invN,
        float* scal, int* flags, float* __restrict__ out, int B, int RPB) {
    __shared__ float rowW[RMAX];
    __shared__ float redL[TPB / 64];

    const int tid = threadIdx.x;
    const int chunk = blockIdx.x / NRBLK;
    const int rblk = blockIdx.x % NRBLK;
    const int c0 = chunk * CCH;
    const int rbase = rblk * RPB;
    const int rows = min(min(RPB, B - rbase), RMAX);
    const int mx = flags[1];   // uniform

    for (int r = tid; r < rows; r += TPB) rowW[r] = invN[target[rbase + r]];
    __syncthreads();

    const int ccS = min(tid, CCH - 1);
    const int c = c0 + ccS;
    const float invc = (tid < CCH) ? invN[c] : 0.f;  // zeroes invalid lanes at the end

    float acc = 0.f;
    const float4* tp4 = (const float4*)(thrP + (size_t)c * PADF);
    if (mx <= 16) {
        BODY(4)
    } else if (mx <= 24) {
        BODY(6)
    } else if (mx <= 32) {
        BODY(8)
    } else {
        // correctness fallback (count in 33..64): serial global reads, L2-cached
        const float* tg = thrP + (size_t)c * PADF;
        for (int r = 0; r < rows; ++r) {
            const float p = pred[(size_t)(rbase + r) * CCLS + c];
            float s = 0.f;
            for (int k = 0; k < PADF; ++k) s += fminf(p, tg[k]);
            acc = fmaf(fmaf((float)PADF, p, -s), rowW[r], acc);
        }
    }
    acc *= invc;

    for (int o = 32; o; o >>= 1) acc += __shfl_down(acc, o);
    if ((tid & 63) == 0) redL[tid >> 6] = acc;
    __syncthreads();
    if (tid == 0) {
        float ssum = 0.f;
#pragma unroll
        for (int k = 0; k < TPB / 64; ++k) ssum += redL[k];
        atomicAdd(&scal[1], ssum);
        __threadfence();
        int done = atomicAdd(&flags[0], 1);
        if (done == (int)gridDim.x - 1) {   // last block finalizes
            float tot = atomicAdd(&scal[1], 0.f);
            float D = scal[2];
            float E = scal[0];
            out[0] = (tot - D) / (E * (E - 1.0f));
        }
    }
}

extern "C" void kernel_launch(void* const* d_in, const int* in_sizes, int n_in,
                              void* d_out, int out_size, void* d_ws, size_t ws_size,
                              hipStream_t stream) {
    const float* pred = (const float*)d_in[0];
    const int* target = (const int*)d_in[1];
    const int B = in_sizes[1];  // 12288

    char* ws = (char*)d_ws;
    int* fill    = (int*)(ws + 0);        // 1000 ints
    float* invN  = (float*)(ws + 4096);   // 1000 floats
    float* scal  = (float*)(ws + 8192);   // [0]=E, [1]=acc, [2]=diag
    int* flags   = (int*)(ws + 8320);     // [0]=counter, [1]=maxcnt
    float* thrP  = (float*)(ws + 16384);  // 1000*64 floats (256KB), FLT_MAX padded

    const int gb = (B + 255) / 256;
    const int RPB = (B + NRBLK - 1) / NRBLK;

    k_init<<<(CCLS * PADF / 4 + 255) / 256, 256, 0, stream>>>((float4*)thrP, fill, scal, flags);
    k_scatter<<<gb, 256, 0, stream>>>(pred, target, fill, thrP, B);
    k_diag<<<(CCLS * 64 + 255) / 256, 256, 0, stream>>>(fill, thrP, invN, scal, flags);
    k_main<<<NCH * NRBLK, TPB, 0, stream>>>(pred, target, thrP, invN,
                                            scal, flags, (float*)d_out, B, RPB);
}